// Round 13
// baseline (313.729 us; speedup 1.0000x reference)
//
#include <hip/hip_runtime.h>
#include <hip/hip_bf16.h>

typedef __bf16 bf16_t;
typedef bf16_t bf16x8 __attribute__((ext_vector_type(8)));
typedef float f32x4 __attribute__((ext_vector_type(4)));
typedef unsigned short u16;
typedef unsigned int u32;

static __device__ __forceinline__ u16 f2bf(float f) {
    __hip_bfloat16 h = __float2bfloat16(f);
    return __builtin_bit_cast(u16, h);
}
// float -> __bf16 with RNE via bit-cast (NOT integer conversion!)
static __device__ __forceinline__ bf16_t fb(float f) {
    return __builtin_bit_cast(bf16_t, f2bf(f));
}
static __device__ __forceinline__ float bf2f(u16 u) {
    u32 x = ((u32)u) << 16;
    return __builtin_bit_cast(float, x);
}
static __device__ __forceinline__ float lo32(u32 p) { return __builtin_bit_cast(float, p << 16); }
static __device__ __forceinline__ float hi32(u32 p) { return __builtin_bit_cast(float, p & 0xffff0000u); }
// soft threshold via clamp: v - clamp(v, -l, l); fuses to v_med3
static __device__ __forceinline__ float softthr(float v, float l, float nl) {
    return v - fmaxf(nl, fminf(v, l));
}

// trivial: Dict copy to out[2]
__global__ __launch_bounds__(256) void copy_dict(const float* __restrict__ Dict,
                                                 float* __restrict__ outd)
{
    int i = blockIdx.x * 256 + threadIdx.x;   // 65536 total
    outd[i] = Dict[i];
}

// ---- fused LISTA: rank-128 factored, dict split across 16 waves ----
// z_{t+1} = ST( z_t + (x - z_t @ D^T) @ D / L ),  z_0 = ST(x @ D)
// 1024 threads = 16 waves, 32 px/block.
// __launch_bounds__(1024, 1): 1 block/CU = 16 waves = 4 waves/SIMD, VGPR cap 128.
// (2nd arg is minBlocksPerCU — (1024,4) would cap VGPRs at 64 and spill; R12 evidence.)
// G1: wave (dg 0..7, ag 0..1): partial[16 dims][32 px] over ag's 256 atoms.
// reduce: r = (x + p0 + p1) / L
// G2: wave covers 32 atoms: accz[2][2] (fp32 regs) IS z. 16 MFMA/wave/GEMM.
__global__ __launch_bounds__(1024, 1)
void lista_main(const float* __restrict__ x,
                const float* __restrict__ Dict,    // fp32 [128][512]
                const float* __restrict__ alpha,
                const float* __restrict__ Lp,
                const int* __restrict__ nip,
                float* __restrict__ outz,          // [32][512][1024]
                float* __restrict__ outr)          // [32][128][1024]
{
    __shared__ __align__(16) u16 zl[32 * 512];   // 32 KB z bf16 [px][atom]
    __shared__ __align__(16) u16 rl[32 * 128];   // 8 KB  r bf16 [px][dim]
    __shared__ __align__(16) u16 xs[32 * 128];   // 8 KB  x bf16 [px][dim]
    __shared__ __align__(16) u16 pb[32 * 256];   // 16 KB partials bf16 [px][ag][dim]

    const int t = threadIdx.x;
    const int lane = t & 63;
    const int l15 = lane & 15;
    const int lg = lane >> 4;            // 0..3
    const int wave = t >> 6;             // 0..15
    const int dg = wave >> 1;            // 0..7 : G1 dim-group (16 dims)
    const int ag = wave & 1;             // 0..1 : G1 atom-group (256 atoms)
    const int atw = wave << 5;           // G2 atom base (32 atoms/wave)
    const int bb = blockIdx.x >> 5;             // batch
    const int hw0 = (blockIdx.x & 31) << 5;     // 32-pixel base
    const float invL = 1.0f / Lp[0];
    const int niter = nip[0];

    // ---- stage xs = bf16(x) [px][dim] swizzled ----
    for (int i = t; i < 32 * 128; i += 1024) {
        int d = i >> 5, px = i & 31;
        xs[((px << 7) + d) ^ ((px & 7) << 3)] =
            f2bf(x[((bb * 128 + d) << 10) + hw0 + px]);
    }

    // thresholds at G2 C columns (px = nt*16 + l15)
    float thr[2], nthr[2];
#pragma unroll
    for (int nt = 0; nt < 2; ++nt) {
        thr[nt] = alpha[hw0 + nt * 16 + l15] * invL;
        nthr[nt] = -thr[nt];
    }

    // ---- dict fragments -> registers (once) ----
    // G1 A: -D[dg*16+l15][ag*256+kt*32+lg*8+j]  (row-contiguous) : 32 VGPR
    bf16x8 g1a[8];
    {
        const float* drow = Dict + ((dg * 16 + l15) << 9) + ag * 256 + lg * 8;
#pragma unroll
        for (int kt = 0; kt < 8; ++kt) {
            f32x4 c0 = *reinterpret_cast<const f32x4*>(drow + kt * 32);
            f32x4 c1 = *reinterpret_cast<const f32x4*>(drow + kt * 32 + 4);
#pragma unroll
            for (int j = 0; j < 4; ++j) {
                g1a[kt][j] = fb(-c0[j]);
                g1a[kt][j + 4] = fb(-c1[j]);
            }
        }
    }
    // G2 A: D^T[atw+at2*16+l15][kt*32+lg*8+j] (column gather, once) : 32 VGPR
    bf16x8 g2a[2][4];
#pragma unroll
    for (int at2 = 0; at2 < 2; ++at2)
#pragma unroll
        for (int kt = 0; kt < 4; ++kt)
#pragma unroll
            for (int j = 0; j < 8; ++j)
                g2a[at2][kt][j] = fb(Dict[((kt * 32 + lg * 8 + j) << 9) + atw + at2 * 16 + l15]);

    __syncthreads();

    // persistent fp32 z: accz[at2][nt] covers [atw+at2*16 atoms][nt*16 px]
    f32x4 accz[2][2];
#pragma unroll
    for (int at2 = 0; at2 < 2; ++at2)
#pragma unroll
        for (int nt = 0; nt < 2; ++nt)
            accz[at2][nt] = f32x4{0.f, 0.f, 0.f, 0.f};

    const int sw0 = (l15 & 7) << 3;            // swizzle for px = l15 (px<16: px&7 = l15&7)

    // G2: accz += D^T @ bsrc^T; ST; write z bf16 to zl (4 indep chains of 4)
    auto run_g2 = [&](const u16* __restrict__ bsrc) {
#pragma unroll
        for (int kt = 0; kt < 4; ++kt) {
            bf16x8 Bf0 = *reinterpret_cast<const bf16x8*>(
                &bsrc[((l15 << 7) + kt * 32 + lg * 8) ^ sw0]);
            bf16x8 Bf1 = *reinterpret_cast<const bf16x8*>(
                &bsrc[(((16 + l15) << 7) + kt * 32 + lg * 8) ^ sw0]);
            accz[0][0] = __builtin_amdgcn_mfma_f32_16x16x32_bf16(g2a[0][kt], Bf0, accz[0][0], 0, 0, 0);
            accz[0][1] = __builtin_amdgcn_mfma_f32_16x16x32_bf16(g2a[0][kt], Bf1, accz[0][1], 0, 0, 0);
            accz[1][0] = __builtin_amdgcn_mfma_f32_16x16x32_bf16(g2a[1][kt], Bf0, accz[1][0], 0, 0, 0);
            accz[1][1] = __builtin_amdgcn_mfma_f32_16x16x32_bf16(g2a[1][kt], Bf1, accz[1][1], 0, 0, 0);
        }
#pragma unroll
        for (int at2 = 0; at2 < 2; ++at2)
#pragma unroll
            for (int nt = 0; nt < 2; ++nt) {
                int px = nt * 16 + l15;
                f32x4 a = accz[at2][nt];
                a[0] = softthr(a[0], thr[nt], nthr[nt]);
                a[1] = softthr(a[1], thr[nt], nthr[nt]);
                a[2] = softthr(a[2], thr[nt], nthr[nt]);
                a[3] = softthr(a[3], thr[nt], nthr[nt]);
                accz[at2][nt] = a;
                uint2 pk;
                pk.x = (u32)f2bf(a[0]) | ((u32)f2bf(a[1]) << 16);
                pk.y = (u32)f2bf(a[2]) | ((u32)f2bf(a[3]) << 16);
                *reinterpret_cast<uint2*>(
                    &zl[((px << 9) + atw + at2 * 16 + lg * 4) ^ sw0]) = pk;
            }
    };

    // G1: partial[16 dims][32 px] over ag's 256 atoms -> pb (2 chains of 8)
    auto run_g1 = [&]() {
        f32x4 a1p0 = f32x4{0.f, 0.f, 0.f, 0.f};
        f32x4 a1p1 = f32x4{0.f, 0.f, 0.f, 0.f};
#pragma unroll
        for (int kt = 0; kt < 8; ++kt) {
            bf16x8 Bf0 = *reinterpret_cast<const bf16x8*>(
                &zl[((l15 << 9) + (ag << 8) + kt * 32 + lg * 8) ^ sw0]);
            bf16x8 Bf1 = *reinterpret_cast<const bf16x8*>(
                &zl[(((16 + l15) << 9) + (ag << 8) + kt * 32 + lg * 8) ^ sw0]);
            a1p0 = __builtin_amdgcn_mfma_f32_16x16x32_bf16(g1a[kt], Bf0, a1p0, 0, 0, 0);
            a1p1 = __builtin_amdgcn_mfma_f32_16x16x32_bf16(g1a[kt], Bf1, a1p1, 0, 0, 0);
        }
        const int d0 = dg * 16 + lg * 4;
        uint2 pk0, pk1;
        pk0.x = (u32)f2bf(a1p0[0]) | ((u32)f2bf(a1p0[1]) << 16);
        pk0.y = (u32)f2bf(a1p0[2]) | ((u32)f2bf(a1p0[3]) << 16);
        pk1.x = (u32)f2bf(a1p1[0]) | ((u32)f2bf(a1p1[1]) << 16);
        pk1.y = (u32)f2bf(a1p1[2]) | ((u32)f2bf(a1p1[3]) << 16);
        *reinterpret_cast<uint2*>(
            &pb[((l15 << 8) + (ag << 7) + d0) ^ sw0]) = pk0;
        *reinterpret_cast<uint2*>(
            &pb[(((16 + l15) << 8) + (ag << 7) + d0) ^ sw0]) = pk1;
    };

    // reduce: r = (x + p0 + p1) * invL -> rl  (1024 tasks of 4 elems)
    auto run_reduce = [&]() {
        const int px = t >> 5;
        const int d0 = (t & 31) << 2;
        const int sw = (px & 7) << 3;
        uint2 P0 = *reinterpret_cast<const uint2*>(&pb[((px << 8) + d0) ^ sw]);
        uint2 P1 = *reinterpret_cast<const uint2*>(&pb[((px << 8) + 128 + d0) ^ sw]);
        uint2 XV = *reinterpret_cast<const uint2*>(&xs[((px << 7) + d0) ^ sw]);
        float s0 = lo32(XV.x) + (lo32(P0.x) + lo32(P1.x));
        float s1 = hi32(XV.x) + (hi32(P0.x) + hi32(P1.x));
        float s2 = lo32(XV.y) + (lo32(P0.y) + lo32(P1.y));
        float s3 = hi32(XV.y) + (hi32(P0.y) + hi32(P1.y));
        uint2 rv;
        rv.x = (u32)f2bf(s0 * invL) | ((u32)f2bf(s1 * invL) << 16);
        rv.y = (u32)f2bf(s2 * invL) | ((u32)f2bf(s3 * invL) << 16);
        *reinterpret_cast<uint2*>(&rl[((px << 7) + d0) ^ sw]) = rv;
    };

    // ---- it 0: z0 = ST(x @ D) ----
    run_g2(xs);
    __syncthreads();

    // ---- main loop ----
    for (int it = 1; it <= niter; ++it) {
        run_g1();
        __syncthreads();
        run_reduce();
        __syncthreads();
        run_g2(rl);
        __syncthreads();
    }

    // ---- final G1 -> partials; recon = -(p0 + p1) ----
    run_g1();
    __syncthreads();

    float rec[4];
    {
        const int px = t >> 5;
        const int d0 = (t & 31) << 2;
        const int sw = (px & 7) << 3;
        uint2 P0 = *reinterpret_cast<const uint2*>(&pb[((px << 8) + d0) ^ sw]);
        uint2 P1 = *reinterpret_cast<const uint2*>(&pb[((px << 8) + 128 + d0) ^ sw]);
        rec[0] = -(lo32(P0.x) + lo32(P1.x));
        rec[1] = -(hi32(P0.x) + hi32(P1.x));
        rec[2] = -(lo32(P0.y) + lo32(P1.y));
        rec[3] = -(hi32(P0.y) + hi32(P1.y));
    }

    // ---- store z from zl (nontemporal, coalesced) ----
    for (int i = t; i < 32 * 512; i += 1024) {
        int a = i >> 5, px = i & 31;
        float zv = bf2f(zl[((px << 9) + a) ^ ((px & 7) << 3)]);
        __builtin_nontemporal_store(zv, &outz[((bb * 512 + a) << 10) + hw0 + px]);
    }
    __syncthreads();   // rec extracted; safe to overwrite pb as fp32

    // ---- stage recon fp32 [px][dim] swizzled into pb region (16 KB) ----
    {
        float* wf = reinterpret_cast<float*>(pb);
        const int px = t >> 5;
        const int d0 = (t & 31) << 2;
        const int swf = (px & 7) << 2;
        f32x4 rv{rec[0], rec[1], rec[2], rec[3]};
        *reinterpret_cast<f32x4*>(&wf[((px << 7) + d0) ^ swf]) = rv;
    }
    __syncthreads();

    // ---- store x_recon (nontemporal, coalesced) ----
    {
        const float* wf = reinterpret_cast<const float*>(pb);
        for (int i = t; i < 32 * 128; i += 1024) {
            int d = i >> 5, px = i & 31;
            __builtin_nontemporal_store(wf[((px << 7) + d) ^ ((px & 7) << 2)],
                                        &outr[((bb * 128 + d) << 10) + hw0 + px]);
        }
    }
}

extern "C" void kernel_launch(void* const* d_in, const int* in_sizes, int n_in,
                              void* d_out, int out_size, void* d_ws, size_t ws_size,
                              hipStream_t stream)
{
    const float* x     = (const float*)d_in[0];
    const float* Dict  = (const float*)d_in[1];
    const float* alpha = (const float*)d_in[2];
    const float* Lp    = (const float*)d_in[3];
    const int*   nip   = (const int*)d_in[4];

    float* outz = (float*)d_out;                 // [32,512,32,32]
    float* outr = outz + 32 * 512 * 1024;        // [32,128,32,32]
    float* outd = outr + 32 * 128 * 1024;        // [128,512]

    copy_dict<<<dim3(256), dim3(256), 0, stream>>>(Dict, outd);
    lista_main<<<dim3(1024), dim3(1024), 0, stream>>>(x, Dict, alpha, Lp, nip,
                                                      outz, outr);
}

// Round 14
// 210.240 us; speedup vs baseline: 1.4922x; 1.4922x over previous
//
#include <hip/hip_runtime.h>
#include <hip/hip_bf16.h>

typedef __bf16 bf16_t;
typedef bf16_t bf16x2 __attribute__((ext_vector_type(2)));
typedef bf16_t bf16x8 __attribute__((ext_vector_type(8)));
typedef float f32x4 __attribute__((ext_vector_type(4)));
typedef unsigned short u16;
typedef unsigned int u32;

// native HW conversions (v_cvt_pk_bf16_f32 path), RNE — same rounding as __float2bfloat16
static __device__ __forceinline__ u16 cvt1(float f) {
    return __builtin_bit_cast(u16, (bf16_t)f);
}
static __device__ __forceinline__ u32 cvt2(float a, float b) {
    bf16x2 t;
    t[0] = (bf16_t)a;
    t[1] = (bf16_t)b;
    return __builtin_bit_cast(u32, t);
}
static __device__ __forceinline__ float bf2f(u16 u) {
    u32 x = ((u32)u) << 16;
    return __builtin_bit_cast(float, x);
}
// soft threshold: v - clamp(v, -l, l) (fuses to v_med3)
static __device__ __forceinline__ float softthr(float v, float l, float nl) {
    return v - fmaxf(nl, fminf(v, l));
}

// trivial: Dict copy to out[2]
__global__ __launch_bounds__(256) void copy_dict(const float* __restrict__ Dict,
                                                 float* __restrict__ outd)
{
    int i = blockIdx.x * 256 + threadIdx.x;   // 65536 total
    outd[i] = Dict[i];
}

// ---- fused LISTA, rank-128 factored, operand-swapped, dict-in-registers ----
// z_{t+1} = ST( z_t + (x - z_t @ D^T) @ D / L ),  z_0 = ST(x @ D)
// All C matrices transposed (m = dim/atom rows, n = pixel cols) so the dict
// is the A operand: per-wave-private, row-contiguous, held in VGPRs.
//  G1: a1[dim][px]  = x^T + (-D) @ z^T     (K=512 atoms)   16 dims/wave
//      -> 4 independent MFMA chains (kt split 0-7 / 8-15), summed at end
//  G2: accz[atom][px] += D^T @ r^T          (K=128 dims)    64 atoms/wave
// accz (fp32 registers) IS z — never rounded across iterations.
// Inner loop touches ONLY LDS (zl 32KB, rl 8KB) and registers.
__global__ __launch_bounds__(512, 2)
void lista_main(const float* __restrict__ x,
                const float* __restrict__ Dict,    // fp32 [128][512]
                const float* __restrict__ alpha,
                const float* __restrict__ Lp,
                const int* __restrict__ nip,
                float* __restrict__ outz,          // [32][512][1024]
                float* __restrict__ outr)          // [32][128][1024]
{
    __shared__ __align__(16) u16 zl[32 * 512];   // z bf16 [px][atom], swizzled
    __shared__ __align__(16) u16 rl[32 * 128];   // r bf16 [px][dim],  swizzled

    const int t = threadIdx.x;
    const int lane = t & 63;
    const int l15 = lane & 15;
    const int lg = lane >> 4;            // 0..3
    const int wave = t >> 6;             // 0..7
    const int bb = blockIdx.x >> 5;             // batch
    const int hw0 = (blockIdx.x & 31) << 5;     // 32-pixel base
    const float invL = 1.0f / Lp[0];
    const int niter = nip[0];

    const int dimb = wave << 4;          // G1: 16 dims per wave
    const int atb  = wave << 6;          // G2: 64 atoms per wave

    // ---- stage rl = bf16(x) [px][dim] (iter-0 G2 B operand, unscaled) ----
    for (int i = t; i < 32 * 128; i += 512) {
        int d = i >> 5, px = i & 31;
        float v = x[((bb * 128 + d) << 10) + hw0 + px];
        rl[((px << 7) + d) ^ ((px & 7) << 3)] = cvt1(v);
    }

    // ---- x fp32 at G1 C positions: dim = dimb+lg*4+rr, px = nt*16+l15 ----
    float xpk[2][4];
#pragma unroll
    for (int nt = 0; nt < 2; ++nt)
#pragma unroll
        for (int rr = 0; rr < 4; ++rr)
            xpk[nt][rr] = x[((bb * 128 + dimb + lg * 4 + rr) << 10) + hw0 + nt * 16 + l15];

    // ---- thresholds at G2 C columns, and negatives ----
    float thr[2], nthr[2];
#pragma unroll
    for (int nt = 0; nt < 2; ++nt) {
        thr[nt] = alpha[hw0 + nt * 16 + l15] * invL;
        nthr[nt] = -thr[nt];
    }

    // ---- dict fragments -> registers (once) ----
    // G1 A: -Dict[dimb+l15][kt*32 + lg*8 + j]   (row-contiguous, float4 x2)
    bf16x8 g1a[16];
    {
        const float* drow = Dict + ((dimb + l15) << 9);
#pragma unroll
        for (int kt = 0; kt < 16; ++kt) {
            f32x4 c0 = *reinterpret_cast<const f32x4*>(&drow[kt * 32 + lg * 8]);
            f32x4 c1 = *reinterpret_cast<const f32x4*>(&drow[kt * 32 + lg * 8 + 4]);
#pragma unroll
            for (int j = 0; j < 4; ++j) {
                g1a[kt][j] = (bf16_t)(-c0[j]);
                g1a[kt][j + 4] = (bf16_t)(-c1[j]);
            }
        }
    }
    // G2 A: Dict^T[atb+at*16+l15][kt*32 + lg*8 + j] = Dict[dim][atom] gather
    bf16x8 g2a[4][4];
#pragma unroll
    for (int at = 0; at < 4; ++at)
#pragma unroll
        for (int kt = 0; kt < 4; ++kt)
#pragma unroll
            for (int j = 0; j < 8; ++j)
                g2a[at][kt][j] = (bf16_t)(Dict[((kt * 32 + lg * 8 + j) << 9) + atb + at * 16 + l15]);

    __syncthreads();

    // G1: a1 = x^T + (-D) @ z^T   (reads all of zl; 4 independent chains)
    auto run_g1 = [&](f32x4 (&a1)[2]) {
        f32x4 c1[2];
#pragma unroll
        for (int nt = 0; nt < 2; ++nt) {
            a1[nt][0] = xpk[nt][0];
            a1[nt][1] = xpk[nt][1];
            a1[nt][2] = xpk[nt][2];
            a1[nt][3] = xpk[nt][3];
            c1[nt] = f32x4{0.f, 0.f, 0.f, 0.f};
        }
#pragma unroll
        for (int kt = 0; kt < 8; ++kt) {
            bf16x8 Bf[2], Bg[2];
#pragma unroll
            for (int nt = 0; nt < 2; ++nt) {
                int px = nt * 16 + l15;
                int sw = (px & 7) << 3;
                Bf[nt] = *reinterpret_cast<const bf16x8*>(
                    &zl[((px << 9) + kt * 32 + lg * 8) ^ sw]);
                Bg[nt] = *reinterpret_cast<const bf16x8*>(
                    &zl[((px << 9) + (kt + 8) * 32 + lg * 8) ^ sw]);
            }
#pragma unroll
            for (int nt = 0; nt < 2; ++nt) {
                a1[nt] = __builtin_amdgcn_mfma_f32_16x16x32_bf16(g1a[kt], Bf[nt], a1[nt], 0, 0, 0);
                c1[nt] = __builtin_amdgcn_mfma_f32_16x16x32_bf16(g1a[kt + 8], Bg[nt], c1[nt], 0, 0, 0);
            }
        }
#pragma unroll
        for (int nt = 0; nt < 2; ++nt)
            a1[nt] += c1[nt];
    };

    f32x4 accz[4][2];
#pragma unroll
    for (int at = 0; at < 4; ++at)
#pragma unroll
        for (int nt = 0; nt < 2; ++nt)
            accz[at][nt] = f32x4{0.f, 0.f, 0.f, 0.f};

    for (int it = 0; it <= niter; ++it) {
        if (it > 0) {
            f32x4 a1[2];
            run_g1(a1);
            // r = a1 * invL -> rl (4 consecutive dims per lane = one b64)
#pragma unroll
            for (int nt = 0; nt < 2; ++nt) {
                int px = nt * 16 + l15;
                uint2 pk;
                pk.x = cvt2(a1[nt][0] * invL, a1[nt][1] * invL);
                pk.y = cvt2(a1[nt][2] * invL, a1[nt][3] * invL);
                *reinterpret_cast<uint2*>(
                    &rl[((px << 7) + dimb + lg * 4) ^ ((px & 7) << 3)]) = pk;
            }
            __syncthreads();   // rl complete; all zl reads done
        }

        // ---- G2: accz += D^T @ r^T  (K=128, all operands reg/LDS) ----
#pragma unroll
        for (int kt = 0; kt < 4; ++kt) {
            bf16x8 Bf[2];
#pragma unroll
            for (int nt = 0; nt < 2; ++nt) {
                int px = nt * 16 + l15;
                Bf[nt] = *reinterpret_cast<const bf16x8*>(
                    &rl[((px << 7) + kt * 32 + lg * 8) ^ ((px & 7) << 3)]);
            }
            __builtin_amdgcn_s_setprio(1);
#pragma unroll
            for (int at = 0; at < 4; ++at)
#pragma unroll
                for (int nt = 0; nt < 2; ++nt)
                    accz[at][nt] = __builtin_amdgcn_mfma_f32_16x16x32_bf16(
                        g2a[at][kt], Bf[nt], accz[at][nt], 0, 0, 0);
            __builtin_amdgcn_s_setprio(0);
        }

        // ---- soft-threshold in place; write z bf16 to zl (b64 per frag) ----
#pragma unroll
        for (int at = 0; at < 4; ++at)
#pragma unroll
            for (int nt = 0; nt < 2; ++nt) {
                int px = nt * 16 + l15;
                f32x4 a = accz[at][nt];
                a[0] = softthr(a[0], thr[nt], nthr[nt]);
                a[1] = softthr(a[1], thr[nt], nthr[nt]);
                a[2] = softthr(a[2], thr[nt], nthr[nt]);
                a[3] = softthr(a[3], thr[nt], nthr[nt]);
                accz[at][nt] = a;
                uint2 pk;
                pk.x = cvt2(a[0], a[1]);
                pk.y = cvt2(a[2], a[3]);
                *reinterpret_cast<uint2*>(
                    &zl[((px << 9) + atb + at * 16 + lg * 4) ^ ((px & 7) << 3)]) = pk;
            }
        __syncthreads();   // zl ready for next G1 (rl free)
    }

    // ---- final G1: x_recon = x - a1 = z @ D^T ----
    f32x4 a1[2];
    run_g1(a1);

    // ---- store z from zl (nontemporal, coalesced 128B segments) ----
    for (int i = t; i < 32 * 512; i += 512) {
        int a = i >> 5, px = i & 31;
        float zv = bf2f(zl[((px << 9) + a) ^ ((px & 7) << 3)]);
        __builtin_nontemporal_store(zv, &outz[((bb * 512 + a) << 10) + hw0 + px]);
    }
    __syncthreads();   // zl reads done before overwrite

    // ---- stage x_recon fp32 [px][dim] swizzled in zl front (16 KB) ----
    float* wf = reinterpret_cast<float*>(zl);
#pragma unroll
    for (int nt = 0; nt < 2; ++nt) {
        int px = nt * 16 + l15;
#pragma unroll
        for (int rr = 0; rr < 4; ++rr)
            wf[((px << 7) + dimb + lg * 4 + rr) ^ ((px & 7) << 2)] = xpk[nt][rr] - a1[nt][rr];
    }
    __syncthreads();

    // ---- store x_recon (nontemporal, coalesced) ----
    for (int i = t; i < 32 * 128; i += 512) {
        int d = i >> 5, px = i & 31;
        __builtin_nontemporal_store(wf[((px << 7) + d) ^ ((px & 7) << 2)],
                                    &outr[((bb * 128 + d) << 10) + hw0 + px]);
    }
}

extern "C" void kernel_launch(void* const* d_in, const int* in_sizes, int n_in,
                              void* d_out, int out_size, void* d_ws, size_t ws_size,
                              hipStream_t stream)
{
    const float* x     = (const float*)d_in[0];
    const float* Dict  = (const float*)d_in[1];
    const float* alpha = (const float*)d_in[2];
    const float* Lp    = (const float*)d_in[3];
    const int*   nip   = (const int*)d_in[4];

    float* outz = (float*)d_out;                 // [32,512,32,32]
    float* outr = outz + 32 * 512 * 1024;        // [32,128,32,32]
    float* outd = outr + 32 * 128 * 1024;        // [128,512]

    copy_dict<<<dim3(256), dim3(256), 0, stream>>>(Dict, outd);
    lista_main<<<dim3(1024), dim3(512), 0, stream>>>(x, Dict, alpha, Lp, nip,
                                                     outz, outr);
}